// Round 7
// baseline (254.450 us; speedup 1.0000x reference)
//
#include <hip/hip_runtime.h>
#include <hip/hip_bf16.h>

#define Bdim 512
#define Sdim 50
#define Hdim 512
#define Ndim 20000
#define Kdim2 1024   // 2*H
#define SEENW 640    // u32 words per row for the seen-bitmask (20000 bits -> 625, pad 640)

typedef __bf16 bf16x8 __attribute__((ext_vector_type(8)));
typedef float f32x4 __attribute__((ext_vector_type(4)));
typedef unsigned short u16;

#define AS1 __attribute__((address_space(1)))
#define AS3 __attribute__((address_space(3)))

__device__ __forceinline__ u16 f2bf(float f) {
  unsigned u = __builtin_bit_cast(unsigned, f);
  u = (u + 0x7fffu + ((u >> 16) & 1u)) >> 16;   // RNE
  return (u16)u;
}
__device__ __forceinline__ float bf2f(u16 v) {
  unsigned u = ((unsigned)v) << 16;
  return __builtin_bit_cast(float, u);
}
// HW packed fp32->bf16 (RNE), lo -> [15:0], hi -> [31:16]
__device__ __forceinline__ unsigned cvt_pk_bf16(float lo, float hi) {
  unsigned r;
  asm("v_cvt_pk_bf16_f32 %0, %1, %2" : "=v"(r) : "v"(lo), "v"(hi));
  return r;
}
__device__ __forceinline__ bf16x8 pack8(float4 lo, float4 hi) {
  union { unsigned u[4]; bf16x8 v; } r;
  r.u[0] = cvt_pk_bf16(lo.x, lo.y);
  r.u[1] = cvt_pk_bf16(lo.z, lo.w);
  r.u[2] = cvt_pk_bf16(hi.x, hi.y);
  r.u[3] = cvt_pk_bf16(hi.z, hi.w);
  return r.v;
}

// ---------------- prep: cast last_memory/W_w/U_w + zero scores/lm/seen ----------
__global__ __launch_bounds__(256) void prep_kernel(const float* __restrict__ a, u16* __restrict__ da,
                                                   const float* __restrict__ b, u16* __restrict__ db,
                                                   const float* __restrict__ c, u16* __restrict__ dc,
                                                   float* __restrict__ scores, float* __restrict__ lm,
                                                   unsigned* __restrict__ seen) {
  int i = blockIdx.x * blockDim.x + threadIdx.x;   // 65536 threads, one float4 each
  float4 v; ushort4 o;
  v = reinterpret_cast<const float4*>(a)[i];
  o.x = f2bf(v.x); o.y = f2bf(v.y); o.z = f2bf(v.z); o.w = f2bf(v.w);
  reinterpret_cast<ushort4*>(da)[i] = o;
  v = reinterpret_cast<const float4*>(b)[i];
  o.x = f2bf(v.x); o.y = f2bf(v.y); o.z = f2bf(v.z); o.w = f2bf(v.w);
  reinterpret_cast<ushort4*>(db)[i] = o;
  v = reinterpret_cast<const float4*>(c)[i];
  o.x = f2bf(v.x); o.y = f2bf(v.y); o.z = f2bf(v.z); o.w = f2bf(v.w);
  reinterpret_cast<ushort4*>(dc)[i] = o;
  int stride = gridDim.x * blockDim.x;
  for (int j = i; j < Bdim * Sdim; j += stride) scores[j] = 0.f;
  for (int j = i; j < Bdim * Hdim; j += stride) lm[j] = 0.f;
  for (int j = i; j < Bdim * SEENW; j += stride) seen[j] = 0u;
}

// ---------------- seen-item scatter ----------------
__global__ __launch_bounds__(256) void scatter_kernel(const int* __restrict__ iseq,
                                                      unsigned* __restrict__ seen) {
  int i = blockIdx.x * blockDim.x + threadIdx.x;
  if (i < Bdim * Sdim) {
    int b = i / Sdim;
    int it = iseq[i];
    if (it > 0) atomicOr(&seen[b * SEENW + (it >> 5)], 1u << (it & 31));
  }
}

// ---------------- softmax over S + context readout -> feat (bf16) ----------------
__global__ __launch_bounds__(256) void softmax_ctx_kernel(
    const float* __restrict__ scores, const unsigned char* __restrict__ mask,
    const float* __restrict__ amF, const float* __restrict__ last_memory,
    u16* __restrict__ feat) {
  int b = blockIdx.x;
  __shared__ float alpha[Sdim];
  int tid = threadIdx.x;
  if (tid < 64) {
    float s = -1e30f;
    if (tid < Sdim) {
      s = scores[b * Sdim + tid];
      if (mask[b * Sdim + tid]) s = -1e9f;   // mask is all-false in this problem
    }
    float m = s;
#pragma unroll
    for (int off = 32; off; off >>= 1) m = fmaxf(m, __shfl_xor(m, off));
    float e = (tid < Sdim) ? __expf(s - m) : 0.f;
    float sum = e;
#pragma unroll
    for (int off = 32; off; off >>= 1) sum += __shfl_xor(sum, off);
    if (tid < Sdim) alpha[tid] = e / sum;
  }
  __syncthreads();
  for (int h = tid; h < Hdim; h += 256) {
    const float* amp = amF + ((long)b * Sdim) * Hdim + h;
    float c = 0.f;
#pragma unroll 5
    for (int s = 0; s < Sdim; ++s) c += alpha[s] * amp[(long)s * Hdim];
    feat[b * Kdim2 + h] = f2bf(c);
    feat[b * Kdim2 + Hdim + h] = f2bf(last_memory[b * Hdim + h]);
  }
}

// ---------------- gemm_bt: 2-phase schedule for lm GEMM (EPI0) + scores GEMM (EPI1)
#define BM 256
#define BN 128
#define BK 32

template <int EPI>
__global__ __launch_bounds__(512, 4) void gemm_bt(
    const u16* __restrict__ A, const u16* __restrict__ Bmat,
    const float* __restrict__ Af,
    int M, int N, int K,
    float* __restrict__ out,
    const float* __restrict__ lm, const float* __restrict__ Vw,
    float* __restrict__ scores) {
  __shared__ bf16x8 Asl[2][BM * BK / 8];   // 2 x 1024 chunks of 16B = 32 KB
  __shared__ bf16x8 Bsl[2][BN * BK / 8];   // 2 x  512 chunks of 16B = 16 KB
  const int tid = threadIdx.x;
  const int lane = tid & 63;
  const int wid = tid >> 6;                 // 0..7
  const int wr = wid >> 1, wc = wid & 1;    // 4x2 wave grid, 64x64 per wave
  const int la = lane & 15, lb = lane >> 4;

  int bx, by, kt0, kt1;
  if constexpr (EPI == 0) {
    bx = blockIdx.x; by = blockIdx.y;
    int ktotal = K / BK; int kper = ktotal / gridDim.z;
    kt0 = blockIdx.z * kper; kt1 = kt0 + kper;
  } else {
    int nwg = gridDim.x, bid = blockIdx.x;
    int q = nwg >> 3, r = nwg & 7;
    int x = bid & 7, i = bid >> 3;
    int wgid = (x < r ? x * (q + 1) : r * (q + 1) + (x - r) * q) + i;
    by = wgid >> 2; bx = wgid & 3;          // 4 n-tiles of one A m-panel per XCD
    kt0 = 0; kt1 = K / BK;
  }
  const int m0 = by * BM;
  const int n0 = bx * BN;

  f32x4 acc[4][4];
  const f32x4 zero = {0.f, 0.f, 0.f, 0.f};
#pragma unroll
  for (int i = 0; i < 4; ++i)
#pragma unroll
    for (int j = 0; j < 4; ++j) acc[i][j] = zero;

  const int rw = tid >> 2;
  const int eA = (tid & 3) * 8;
  const int ch = tid & 3;
  int brB = n0 + rw; if (brB > N - 1) brB = N - 1;

  const u16 *gA0 = nullptr, *gA1 = nullptr, *gB = nullptr;
  const float *gAf0 = nullptr, *gAf1 = nullptr;
  if constexpr (EPI == 1) {
    gAf0 = Af + (long)(m0 + rw) * K + eA;
    gAf1 = Af + (long)(m0 + 128 + rw) * K + eA;
  } else {
    gA0 = A + (long)(m0 + rw) * K + eA;
    gA1 = A + (long)(m0 + 128 + rw) * K + eA;
  }
  gB = Bmat + (long)brB * K + eA;

  float4 ra0, ra1, ra2, ra3;   // EPI1: A fp32 staging regs

  auto STAGE_G = [&](int buf, int kt) {
    const int k0 = kt * BK;
    if constexpr (EPI != 1) {
      __builtin_amdgcn_global_load_lds((const AS1 void*)(gA0 + k0),
                                       (AS3 void*)(void*)&Asl[buf][wid * 64], 16, 0, 0);
      __builtin_amdgcn_global_load_lds((const AS1 void*)(gA1 + k0),
                                       (AS3 void*)(void*)&Asl[buf][512 + wid * 64], 16, 0, 0);
    }
    __builtin_amdgcn_global_load_lds((const AS1 void*)(gB + k0),
                                     (AS3 void*)(void*)&Bsl[buf][wid * 64], 16, 0, 0);
  };
  auto LOADR = [&](int kt) {
    const int k0 = kt * BK;
    if constexpr (EPI == 1) {
      ra0 = *reinterpret_cast<const float4*>(gAf0 + k0);
      ra1 = *reinterpret_cast<const float4*>(gAf0 + k0 + 4);
      ra2 = *reinterpret_cast<const float4*>(gAf1 + k0);
      ra3 = *reinterpret_cast<const float4*>(gAf1 + k0 + 4);
    }
  };
  auto WRITER = [&](int buf) {
    if constexpr (EPI == 1) {
      Asl[buf][rw * 4 + ch] = pack8(ra0, ra1);
      Asl[buf][(128 + rw) * 4 + ch] = pack8(ra2, ra3);
    }
  };

  STAGE_G(0, kt0);
  LOADR(kt0);
  WRITER(0);
  __syncthreads();
  int cur = 0;
  for (int kt = kt0; kt < kt1; ++kt) {
    const bool pf = (kt + 1 < kt1);
    if (pf) { STAGE_G(cur ^ 1, kt + 1); LOADR(kt + 1); }

    bf16x8 af[4], bfr[4];
#pragma unroll
    for (int mi = 0; mi < 4; ++mi)
      af[mi] = Asl[cur][(wr * 64 + mi * 16 + la) * 4 + lb];
#pragma unroll
    for (int ni = 0; ni < 4; ++ni)
      bfr[ni] = Bsl[cur][(wc * 64 + ni * 16 + la) * 4 + lb];
#pragma unroll
    for (int mi = 0; mi < 4; ++mi)
#pragma unroll
      for (int ni = 0; ni < 4; ++ni)
        acc[mi][ni] = __builtin_amdgcn_mfma_f32_16x16x32_bf16(af[mi], bfr[ni], acc[mi][ni], 0, 0, 0);

    if (pf) WRITER(cur ^ 1);
    __syncthreads();
    cur ^= 1;
  }

  // C/D layout (verified): col = lane&15, row = (lane>>4)*4 + reg
  if constexpr (EPI == 0) {
#pragma unroll
    for (int mi = 0; mi < 4; ++mi)
#pragma unroll
      for (int i = 0; i < 4; ++i) {
        int r = m0 + wr * 64 + mi * 16 + lb * 4 + i;
#pragma unroll
        for (int ni = 0; ni < 4; ++ni) {
          int c = n0 + wc * 64 + ni * 16 + la;
          atomicAdd(&out[(long)r * N + c], acc[mi][ni][i]);
        }
      }
  }
  if constexpr (EPI == 1) {
#pragma unroll
    for (int mi = 0; mi < 4; ++mi)
#pragma unroll
      for (int i = 0; i < 4; ++i) {
        int r = m0 + wr * 64 + mi * 16 + lb * 4 + i;
        int bidx = r / Sdim;
        float p = 0.f;
#pragma unroll
        for (int ni = 0; ni < 4; ++ni) {
          int c = n0 + wc * 64 + ni * 16 + la;
          float x = acc[mi][ni][i] + lm[bidx * Hdim + c];
          x = fminf(fmaxf(x, -9.f), 9.f);
          float e = __expf(2.f * x);
          p += Vw[c] * ((e - 1.f) / (e + 1.f));
        }
        p += __shfl_xor(p, 1);
        p += __shfl_xor(p, 2);
        p += __shfl_xor(p, 4);
        p += __shfl_xor(p, 8);
        if (la == 0) atomicAdd(&scores[r], p);
      }
  }
}

// ---------------- gemm_logits: barrier-free direct-register GEMM ----------------
// A = feat bf16 (1 MB, L2-resident): per-lane 16B fragment loads, no staging.
// B = E_w fp32 (HBM stream): per-lane 2x float4 per row, cvt_pk -> bf16 frags.
// NO LDS, NO barriers: waves are independent streams -> HBM latency hides via
// TLP (waves slip freely) + compiler pipelining over the unroll window (the
// compiler's counted s_waitcnt scheduling is good when nothing forces a drain).
// Same global access pattern as the LDS path (128B gather per B row), so
// coalescing is unchanged; only the LDS round-trip + barrier coupling is gone.
// XCD swizzle groups the 2 m-tiles of one E_w n-panel per XCD (E read once
// from HBM, L2 serves the reuse).
#define LBM 256
#define LBN 128

__global__ __launch_bounds__(512) void gemm_logits(
    const u16* __restrict__ A, const float* __restrict__ Bf,
    float* __restrict__ out, const unsigned* __restrict__ seen) {
  const int tid = threadIdx.x;
  const int lane = tid & 63;
  const int wid = tid >> 6;
  const int wr = wid >> 1, wc = wid & 1;    // 4x2 waves, 64x64 per wave
  const int la = lane & 15, lb = lane >> 4;

  // bijective XCD swizzle; groups the 2 m-tiles of one E_w n-panel per XCD
  int nwg = gridDim.x, bid = blockIdx.x;
  int q = nwg >> 3, r = nwg & 7;
  int x = bid & 7, i0 = bid >> 3;
  int wgid = (x < r ? x * (q + 1) : r * (q + 1) + (x - r) * q) + i0;
  const int bx = wgid >> 1, by = wgid & 1;
  const int m0 = by * LBM, n0 = bx * LBN;

  f32x4 acc[4][4];
  const f32x4 zero = {0.f, 0.f, 0.f, 0.f};
#pragma unroll
  for (int i = 0; i < 4; ++i)
#pragma unroll
    for (int j = 0; j < 4; ++j) acc[i][j] = zero;

  // fragment pointers: lane reads A rows (m0+wr*64+mi*16+la), 16B at k=lb*8;
  // B rows (n0+wc*64+ni*16+la) fp32, 32B at k=lb*8 (clamped for last n-tile)
  const u16* pa[4];
  const float* pb[4];
#pragma unroll
  for (int mi = 0; mi < 4; ++mi)
    pa[mi] = A + (long)(m0 + wr * 64 + mi * 16 + la) * Kdim2 + lb * 8;
#pragma unroll
  for (int ni = 0; ni < 4; ++ni) {
    int rr = n0 + wc * 64 + ni * 16 + la;
    if (rr > Ndim - 1) rr = Ndim - 1;
    pb[ni] = Bf + (long)rr * Kdim2 + lb * 8;
  }

#pragma unroll 2
  for (int kt = 0; kt < Kdim2 / 32; ++kt) {
    const int k0 = kt * 32;
    bf16x8 af[4], bfr[4];
#pragma unroll
    for (int ni = 0; ni < 4; ++ni) {
      float4 lo = *reinterpret_cast<const float4*>(pb[ni] + k0);
      float4 hi = *reinterpret_cast<const float4*>(pb[ni] + k0 + 4);
      bfr[ni] = pack8(lo, hi);
    }
#pragma unroll
    for (int mi = 0; mi < 4; ++mi)
      af[mi] = *reinterpret_cast<const bf16x8*>(pa[mi] + k0);
#pragma unroll
    for (int mi = 0; mi < 4; ++mi)
#pragma unroll
      for (int ni = 0; ni < 4; ++ni)
        acc[mi][ni] = __builtin_amdgcn_mfma_f32_16x16x32_bf16(af[mi], bfr[ni], acc[mi][ni], 0, 0, 0);
  }

  // epilogue: sigmoid + seen-mask
#pragma unroll
  for (int mi = 0; mi < 4; ++mi)
#pragma unroll
    for (int i = 0; i < 4; ++i) {
      int r = m0 + wr * 64 + mi * 16 + lb * 4 + i;
      long rb = (long)r * Ndim;
#pragma unroll
      for (int ni = 0; ni < 4; ++ni) {
        int c = n0 + wc * 64 + ni * 16 + la;
        if (c < Ndim) {
          unsigned wbits = seen[r * SEENW + (c >> 5)];
          float val = 0.f;
          if (!((wbits >> (c & 31)) & 1u))
            val = 1.f / (1.f + __expf(-acc[mi][ni][i]));
          out[rb + c] = val;
        }
      }
    }
}

// ---------------- launcher ----------------
extern "C" void kernel_launch(void* const* d_in, const int* in_sizes, int n_in,
                              void* d_out, int out_size, void* d_ws, size_t ws_size,
                              hipStream_t stream) {
  (void)in_sizes; (void)n_in; (void)out_size; (void)ws_size;
  const float* all_memory  = (const float*)d_in[0];
  const float* last_memory = (const float*)d_in[1];
  const int*   item_seq    = (const int*)d_in[2];
  const unsigned char* mask = (const unsigned char*)d_in[3];
  const float* U_w = (const float*)d_in[4];
  const float* W_w = (const float*)d_in[5];
  const float* V_w = (const float*)d_in[6];
  const float* E_w = (const float*)d_in[8];
  float* out = (float*)d_out;

  char* w = (char*)d_ws;
  u16* wsFeat = (u16*)w; w += (size_t)Bdim * Kdim2 * 2;         // 1 MB
  u16* wsLast = (u16*)w; w += (size_t)Hdim * Hdim * 2;          // 0.5 MB
  u16* wsW    = (u16*)w; w += (size_t)Hdim * Hdim * 2;
  u16* wsU    = (u16*)w; w += (size_t)Hdim * Hdim * 2;
  float* wsLm     = (float*)w; w += (size_t)Bdim * Hdim * 4;    // 1 MB
  float* wsScores = (float*)w; w += (size_t)Bdim * Sdim * 4;
  unsigned* wsSeen = (unsigned*)w; w += (size_t)Bdim * SEENW * 4;

  prep_kernel<<<256, 256, 0, stream>>>(last_memory, wsLast, W_w, wsW, U_w, wsU,
                                       wsScores, wsLm, wsSeen);
  scatter_kernel<<<100, 256, 0, stream>>>(item_seq, wsSeen);

  // lm = last_memory @ W_w^T   (512x512x512, split-K=4, atomic accumulate)
  gemm_bt<0><<<dim3(Hdim / BN, Bdim / BM, 4), 512, 0, stream>>>(
      wsLast, wsW, nullptr, Bdim, Hdim, Hdim, wsLm, nullptr, nullptr, nullptr);
  // scores += sum_k V[k]*tanh(am + lm)   (25600x512x512), 100 m x 4 n = 400 blocks
  gemm_bt<1><<<dim3((Bdim * Sdim / BM) * (Hdim / BN)), 512, 0, stream>>>(
      nullptr, wsU, all_memory, Bdim * Sdim, Hdim, Hdim, nullptr,
      wsLm, V_w, wsScores);
  softmax_ctx_kernel<<<Bdim, 256, 0, stream>>>(wsScores, mask, all_memory, last_memory, wsFeat);
  // out = sigmoid/mask( feat @ E_w^T )   (512x20000x1024), 157 n x 2 m = 314 blocks
  gemm_logits<<<dim3(((Ndim + LBN - 1) / LBN) * (Bdim / LBM)), 512, 0, stream>>>(
      wsFeat, E_w, out, wsSeen);
}

// Round 8
// 164.954 us; speedup vs baseline: 1.5426x; 1.5426x over previous
//
#include <hip/hip_runtime.h>
#include <hip/hip_bf16.h>

#define Bdim 512
#define Sdim 50
#define Hdim 512
#define Ndim 20000
#define Kdim2 1024   // 2*H
#define SEENW 640    // u32 words per row for the seen-bitmask (20000 bits -> 625, pad 640)

typedef __bf16 bf16x8 __attribute__((ext_vector_type(8)));
typedef float f32x4 __attribute__((ext_vector_type(4)));
typedef unsigned short u16;

#define AS1 __attribute__((address_space(1)))
#define AS3 __attribute__((address_space(3)))

__device__ __forceinline__ u16 f2bf(float f) {
  unsigned u = __builtin_bit_cast(unsigned, f);
  u = (u + 0x7fffu + ((u >> 16) & 1u)) >> 16;   // RNE
  return (u16)u;
}
__device__ __forceinline__ float bf2f(u16 v) {
  unsigned u = ((unsigned)v) << 16;
  return __builtin_bit_cast(float, u);
}
// HW packed fp32->bf16 (RNE), lo -> [15:0], hi -> [31:16]
__device__ __forceinline__ unsigned cvt_pk_bf16(float lo, float hi) {
  unsigned r;
  asm("v_cvt_pk_bf16_f32 %0, %1, %2" : "=v"(r) : "v"(lo), "v"(hi));
  return r;
}
__device__ __forceinline__ bf16x8 pack8(float4 lo, float4 hi) {
  union { unsigned u[4]; bf16x8 v; } r;
  r.u[0] = cvt_pk_bf16(lo.x, lo.y);
  r.u[1] = cvt_pk_bf16(lo.z, lo.w);
  r.u[2] = cvt_pk_bf16(hi.x, hi.y);
  r.u[3] = cvt_pk_bf16(hi.z, hi.w);
  return r.v;
}

// ---------------- prep: cast last_memory/W_w/U_w + zero scores/lm/seen ----------
__global__ __launch_bounds__(256) void prep_kernel(const float* __restrict__ a, u16* __restrict__ da,
                                                   const float* __restrict__ b, u16* __restrict__ db,
                                                   const float* __restrict__ c, u16* __restrict__ dc,
                                                   float* __restrict__ scores, float* __restrict__ lm,
                                                   unsigned* __restrict__ seen) {
  int i = blockIdx.x * blockDim.x + threadIdx.x;   // 65536 threads, one float4 each
  float4 v; ushort4 o;
  v = reinterpret_cast<const float4*>(a)[i];
  o.x = f2bf(v.x); o.y = f2bf(v.y); o.z = f2bf(v.z); o.w = f2bf(v.w);
  reinterpret_cast<ushort4*>(da)[i] = o;
  v = reinterpret_cast<const float4*>(b)[i];
  o.x = f2bf(v.x); o.y = f2bf(v.y); o.z = f2bf(v.z); o.w = f2bf(v.w);
  reinterpret_cast<ushort4*>(db)[i] = o;
  v = reinterpret_cast<const float4*>(c)[i];
  o.x = f2bf(v.x); o.y = f2bf(v.y); o.z = f2bf(v.z); o.w = f2bf(v.w);
  reinterpret_cast<ushort4*>(dc)[i] = o;
  int stride = gridDim.x * blockDim.x;
  for (int j = i; j < Bdim * Sdim; j += stride) scores[j] = 0.f;
  for (int j = i; j < Bdim * Hdim; j += stride) lm[j] = 0.f;
  for (int j = i; j < Bdim * SEENW; j += stride) seen[j] = 0u;
}

// ---------------- seen-item scatter ----------------
__global__ __launch_bounds__(256) void scatter_kernel(const int* __restrict__ iseq,
                                                      unsigned* __restrict__ seen) {
  int i = blockIdx.x * blockDim.x + threadIdx.x;
  if (i < Bdim * Sdim) {
    int b = i / Sdim;
    int it = iseq[i];
    if (it > 0) atomicOr(&seen[b * SEENW + (it >> 5)], 1u << (it & 31));
  }
}

// ---------------- softmax over S + context readout -> feat (bf16) ----------------
__global__ __launch_bounds__(256) void softmax_ctx_kernel(
    const float* __restrict__ scores, const unsigned char* __restrict__ mask,
    const float* __restrict__ amF, const float* __restrict__ last_memory,
    u16* __restrict__ feat) {
  int b = blockIdx.x;
  __shared__ float alpha[Sdim];
  int tid = threadIdx.x;
  if (tid < 64) {
    float s = -1e30f;
    if (tid < Sdim) {
      s = scores[b * Sdim + tid];
      if (mask[b * Sdim + tid]) s = -1e9f;   // mask is all-false in this problem
    }
    float m = s;
#pragma unroll
    for (int off = 32; off; off >>= 1) m = fmaxf(m, __shfl_xor(m, off));
    float e = (tid < Sdim) ? __expf(s - m) : 0.f;
    float sum = e;
#pragma unroll
    for (int off = 32; off; off >>= 1) sum += __shfl_xor(sum, off);
    if (tid < Sdim) alpha[tid] = e / sum;
  }
  __syncthreads();
  for (int h = tid; h < Hdim; h += 256) {
    const float* amp = amF + ((long)b * Sdim) * Hdim + h;
    float c = 0.f;
#pragma unroll 5
    for (int s = 0; s < Sdim; ++s) c += alpha[s] * amp[(long)s * Hdim];
    feat[b * Kdim2 + h] = f2bf(c);
    feat[b * Kdim2 + Hdim + h] = f2bf(last_memory[b * Hdim + h]);
  }
}

// ---------------- gemm_bt: 2-phase schedule for lm GEMM (EPI0) + scores GEMM (EPI1)
#define BM 256
#define BN 128
#define BK 32

template <int EPI>
__global__ __launch_bounds__(512, 4) void gemm_bt(
    const u16* __restrict__ A, const u16* __restrict__ Bmat,
    const float* __restrict__ Af,
    int M, int N, int K,
    float* __restrict__ out,
    const float* __restrict__ lm, const float* __restrict__ Vw,
    float* __restrict__ scores) {
  __shared__ bf16x8 Asl[2][BM * BK / 8];   // 2 x 1024 chunks of 16B = 32 KB
  __shared__ bf16x8 Bsl[2][BN * BK / 8];   // 2 x  512 chunks of 16B = 16 KB
  const int tid = threadIdx.x;
  const int lane = tid & 63;
  const int wid = tid >> 6;                 // 0..7
  const int wr = wid >> 1, wc = wid & 1;    // 4x2 wave grid, 64x64 per wave
  const int la = lane & 15, lb = lane >> 4;

  int bx, by, kt0, kt1;
  if constexpr (EPI == 0) {
    bx = blockIdx.x; by = blockIdx.y;
    int ktotal = K / BK; int kper = ktotal / gridDim.z;
    kt0 = blockIdx.z * kper; kt1 = kt0 + kper;
  } else {
    int nwg = gridDim.x, bid = blockIdx.x;
    int q = nwg >> 3, r = nwg & 7;
    int x = bid & 7, i = bid >> 3;
    int wgid = (x < r ? x * (q + 1) : r * (q + 1) + (x - r) * q) + i;
    by = wgid >> 2; bx = wgid & 3;          // 4 n-tiles of one A m-panel per XCD
    kt0 = 0; kt1 = K / BK;
  }
  const int m0 = by * BM;
  const int n0 = bx * BN;

  f32x4 acc[4][4];
  const f32x4 zero = {0.f, 0.f, 0.f, 0.f};
#pragma unroll
  for (int i = 0; i < 4; ++i)
#pragma unroll
    for (int j = 0; j < 4; ++j) acc[i][j] = zero;

  const int rw = tid >> 2;
  const int eA = (tid & 3) * 8;
  const int ch = tid & 3;
  int brB = n0 + rw; if (brB > N - 1) brB = N - 1;

  const u16 *gA0 = nullptr, *gA1 = nullptr, *gB = nullptr;
  const float *gAf0 = nullptr, *gAf1 = nullptr;
  if constexpr (EPI == 1) {
    gAf0 = Af + (long)(m0 + rw) * K + eA;
    gAf1 = Af + (long)(m0 + 128 + rw) * K + eA;
  } else {
    gA0 = A + (long)(m0 + rw) * K + eA;
    gA1 = A + (long)(m0 + 128 + rw) * K + eA;
  }
  gB = Bmat + (long)brB * K + eA;

  float4 ra0, ra1, ra2, ra3;   // EPI1: A fp32 staging regs

  auto STAGE_G = [&](int buf, int kt) {
    const int k0 = kt * BK;
    if constexpr (EPI != 1) {
      __builtin_amdgcn_global_load_lds((const AS1 void*)(gA0 + k0),
                                       (AS3 void*)(void*)&Asl[buf][wid * 64], 16, 0, 0);
      __builtin_amdgcn_global_load_lds((const AS1 void*)(gA1 + k0),
                                       (AS3 void*)(void*)&Asl[buf][512 + wid * 64], 16, 0, 0);
    }
    __builtin_amdgcn_global_load_lds((const AS1 void*)(gB + k0),
                                     (AS3 void*)(void*)&Bsl[buf][wid * 64], 16, 0, 0);
  };
  auto LOADR = [&](int kt) {
    const int k0 = kt * BK;
    if constexpr (EPI == 1) {
      ra0 = *reinterpret_cast<const float4*>(gAf0 + k0);
      ra1 = *reinterpret_cast<const float4*>(gAf0 + k0 + 4);
      ra2 = *reinterpret_cast<const float4*>(gAf1 + k0);
      ra3 = *reinterpret_cast<const float4*>(gAf1 + k0 + 4);
    }
  };
  auto WRITER = [&](int buf) {
    if constexpr (EPI == 1) {
      Asl[buf][rw * 4 + ch] = pack8(ra0, ra1);
      Asl[buf][(128 + rw) * 4 + ch] = pack8(ra2, ra3);
    }
  };

  STAGE_G(0, kt0);
  LOADR(kt0);
  WRITER(0);
  __syncthreads();
  int cur = 0;
  for (int kt = kt0; kt < kt1; ++kt) {
    const bool pf = (kt + 1 < kt1);
    if (pf) { STAGE_G(cur ^ 1, kt + 1); LOADR(kt + 1); }

    bf16x8 af[4], bfr[4];
#pragma unroll
    for (int mi = 0; mi < 4; ++mi)
      af[mi] = Asl[cur][(wr * 64 + mi * 16 + la) * 4 + lb];
#pragma unroll
    for (int ni = 0; ni < 4; ++ni)
      bfr[ni] = Bsl[cur][(wc * 64 + ni * 16 + la) * 4 + lb];
#pragma unroll
    for (int mi = 0; mi < 4; ++mi)
#pragma unroll
      for (int ni = 0; ni < 4; ++ni)
        acc[mi][ni] = __builtin_amdgcn_mfma_f32_16x16x32_bf16(af[mi], bfr[ni], acc[mi][ni], 0, 0, 0);

    if (pf) WRITER(cur ^ 1);
    __syncthreads();
    cur ^= 1;
  }

  // C/D layout (verified): col = lane&15, row = (lane>>4)*4 + reg
  if constexpr (EPI == 0) {
#pragma unroll
    for (int mi = 0; mi < 4; ++mi)
#pragma unroll
      for (int i = 0; i < 4; ++i) {
        int r = m0 + wr * 64 + mi * 16 + lb * 4 + i;
#pragma unroll
        for (int ni = 0; ni < 4; ++ni) {
          int c = n0 + wc * 64 + ni * 16 + la;
          atomicAdd(&out[(long)r * N + c], acc[mi][ni][i]);
        }
      }
  }
  if constexpr (EPI == 1) {
#pragma unroll
    for (int mi = 0; mi < 4; ++mi)
#pragma unroll
      for (int i = 0; i < 4; ++i) {
        int r = m0 + wr * 64 + mi * 16 + lb * 4 + i;
        int bidx = r / Sdim;
        float p = 0.f;
#pragma unroll
        for (int ni = 0; ni < 4; ++ni) {
          int c = n0 + wc * 64 + ni * 16 + la;
          float x = acc[mi][ni][i] + lm[bidx * Hdim + c];
          x = fminf(fmaxf(x, -9.f), 9.f);
          float e = __expf(2.f * x);
          p += Vw[c] * ((e - 1.f) / (e + 1.f));
        }
        p += __shfl_xor(p, 1);
        p += __shfl_xor(p, 2);
        p += __shfl_xor(p, 4);
        p += __shfl_xor(p, 8);
        if (la == 0) atomicAdd(&scores[r], p);
      }
  }
}

// ---------------- gemm_logits: deep-pipelined logits GEMM ----------------
// A = feat bf16: 3-slot LDS ring via global_load_lds (pre-swizzled source),
// staged 2 tiles ahead. B = E_w fp32: 4-BANK register pipeline -- iter kt
// issues loads for tile kt+4; the cvt+ds_write at iter kt consumes tile kt+1,
// issued at iter kt-3 => ~3 iterations (~600-900 cyc) of HBM latency cover
// (round-6's 1-deep pipeline was the failure: only ~1 iter of cover).
// Counted vmcnt: 4 vm ops/iter (2 A-gload_lds + 2 B-loads). Compiler's wait
// before pack8 = vmcnt(12) (retires exactly through B(kt+1)); our vmcnt(6)
// before the raw s_barrier retires A(kt+1) while keeping B(kt+3),A(kt+2),
// B(kt+4) in flight -- never drains to 0 in the loop. Named banks (rule #20),
// manual unroll-4 (NT=32), sched_barrier(0) fences pin issue order.
#define LBM 256
#define LBN 128
#define LBK 32

__global__ __launch_bounds__(512, 2) void gemm_logits(
    const u16* __restrict__ A, const float* __restrict__ Bf,
    float* __restrict__ out, const unsigned* __restrict__ seen) {
  __shared__ bf16x8 Asl[3][LBM * LBK / 8];   // 3 x 16 KB
  __shared__ bf16x8 Bsl[2][LBN * LBK / 8];   // 2 x  8 KB
  const int tid = threadIdx.x;
  const int lane = tid & 63;
  const int wid = tid >> 6;
  const int wr = wid >> 1, wc = wid & 1;    // 4x2 waves, 64x64 per wave
  const int la = lane & 15, lb = lane >> 4;
  const int kch = lb ^ (la & 3);            // swizzled k-chunk for LDS reads
  const int NT = Kdim2 / LBK;               // 32

  // bijective XCD swizzle; groups the 2 m-tiles of one E_w n-panel per XCD
  int nwg = gridDim.x, bid = blockIdx.x;
  int q = nwg >> 3, r = nwg & 7;
  int x = bid & 7, i0 = bid >> 3;
  int wgid = (x < r ? x * (q + 1) : r * (q + 1) + (x - r) * q) + i0;
  const int bx = wgid >> 1, by = wgid & 1;
  const int m0 = by * LBM, n0 = bx * LBN;

  f32x4 acc[4][4];
  const f32x4 zero = {0.f, 0.f, 0.f, 0.f};
#pragma unroll
  for (int i = 0; i < 4; ++i)
#pragma unroll
    for (int j = 0; j < 4; ++j) acc[i][j] = zero;

  const int rw = tid >> 2;                  // 0..127
  const int ch = tid & 3;
  const int swz = ch ^ (rw & 3);            // pre-swizzled source / LDS chunk
  int brB = n0 + rw; if (brB > Ndim - 1) brB = Ndim - 1;
  const u16* gA0 = A + (long)(m0 + rw) * Kdim2 + swz * 8;
  const u16* gA1 = A + (long)(m0 + 128 + rw) * Kdim2 + swz * 8;
  const float* gBf = Bf + (long)brB * Kdim2 + ch * 8;

  auto STAGE_A = [&](int kt, int slot) {
    int t = kt > NT - 1 ? NT - 1 : kt;
    const int k0 = t * LBK;
    __builtin_amdgcn_global_load_lds((const AS1 void*)(gA0 + k0),
                                     (AS3 void*)(void*)&Asl[slot][wid * 64], 16, 0, 0);
    __builtin_amdgcn_global_load_lds((const AS1 void*)(gA1 + k0),
                                     (AS3 void*)(void*)&Asl[slot][512 + wid * 64], 16, 0, 0);
  };
  auto BLOAD = [&](int kt, float4& lo, float4& hi) {
    int t = kt > NT - 1 ? NT - 1 : kt;
    lo = *reinterpret_cast<const float4*>(gBf + t * LBK);
    hi = *reinterpret_cast<const float4*>(gBf + t * LBK + 4);
  };
  auto COMP = [&](int slA, int slB) {
    bf16x8 af[4], bfr[4];
#pragma unroll
    for (int mi = 0; mi < 4; ++mi)
      af[mi] = Asl[slA][(wr * 64 + mi * 16 + la) * 4 + kch];
#pragma unroll
    for (int ni = 0; ni < 4; ++ni)
      bfr[ni] = Bsl[slB][(wc * 64 + ni * 16 + la) * 4 + kch];
#pragma unroll
    for (int mi = 0; mi < 4; ++mi)
#pragma unroll
      for (int ni = 0; ni < 4; ++ni)
        acc[mi][ni] = __builtin_amdgcn_mfma_f32_16x16x32_bf16(af[mi], bfr[ni], acc[mi][ni], 0, 0, 0);
  };

  float4 b0lo, b0hi, b1lo, b1hi, b2lo, b2hi, b3lo, b3hi;   // 4 named banks

  // ---- prologue: A(0),A(1) staged; B tiles 0..3 in flight ----
  STAGE_A(0, 0);
  STAGE_A(1, 1);
  __builtin_amdgcn_sched_barrier(0);
  BLOAD(0, b0lo, b0hi);
  BLOAD(1, b1lo, b1hi);
  BLOAD(2, b2lo, b2hi);
  BLOAD(3, b3lo, b3hi);
  __builtin_amdgcn_sched_barrier(0);
  Bsl[0][rw * 4 + swz] = pack8(b0lo, b0hi);      // compiler waits vmcnt for b0
  asm volatile("s_waitcnt vmcnt(10) lgkmcnt(0)" ::: "memory");  // A(0) landed
  __builtin_amdgcn_sched_barrier(0);
  __builtin_amdgcn_s_barrier();
  __builtin_amdgcn_sched_barrier(0);

  int sC = 0, sS = 2;   // A ring: compute slot (tile kt), stage slot (tile kt+2)
  auto ITER = [&](int kt, float4& ldlo, float4& ldhi, float4& stlo, float4& sthi) {
    STAGE_A(kt + 2, sS);                     // 2 gload_lds
    __builtin_amdgcn_sched_barrier(0);
    BLOAD(kt + 4, ldlo, ldhi);               // 2 fp32 loads, 3-iter cover
    __builtin_amdgcn_sched_barrier(0);
    COMP(sC, kt & 1);
    __builtin_amdgcn_sched_barrier(0);
    Bsl[(kt + 1) & 1][rw * 4 + swz] = pack8(stlo, sthi);  // tile kt+1 -> LDS
    asm volatile("s_waitcnt vmcnt(6) lgkmcnt(0)" ::: "memory");
    __builtin_amdgcn_sched_barrier(0);
    __builtin_amdgcn_s_barrier();            // slot kt+1 (A and B) ready
    __builtin_amdgcn_sched_barrier(0);
    sC = (sC == 2) ? 0 : sC + 1;
    sS = (sS == 2) ? 0 : sS + 1;
  };

  for (int kt = 0; kt < NT; kt += 4) {
    ITER(kt,     b0lo, b0hi, b1lo, b1hi);
    ITER(kt + 1, b1lo, b1hi, b2lo, b2hi);
    ITER(kt + 2, b2lo, b2hi, b3lo, b3hi);
    ITER(kt + 3, b3lo, b3hi, b0lo, b0hi);
  }
  asm volatile("s_waitcnt vmcnt(0)" ::: "memory");   // drain tail

  // epilogue: sigmoid + seen-mask
#pragma unroll
  for (int mi = 0; mi < 4; ++mi)
#pragma unroll
    for (int i = 0; i < 4; ++i) {
      int r = m0 + wr * 64 + mi * 16 + lb * 4 + i;
      long rb = (long)r * Ndim;
#pragma unroll
      for (int ni = 0; ni < 4; ++ni) {
        int c = n0 + wc * 64 + ni * 16 + la;
        if (c < Ndim) {
          unsigned wbits = seen[r * SEENW + (c >> 5)];
          float val = 0.f;
          if (!((wbits >> (c & 31)) & 1u))
            val = 1.f / (1.f + __expf(-acc[mi][ni][i]));
          out[rb + c] = val;
        }
      }
    }
}

// ---------------- launcher ----------------
extern "C" void kernel_launch(void* const* d_in, const int* in_sizes, int n_in,
                              void* d_out, int out_size, void* d_ws, size_t ws_size,
                              hipStream_t stream) {
  (void)in_sizes; (void)n_in; (void)out_size; (void)ws_size;
  const float* all_memory  = (const float*)d_in[0];
  const float* last_memory = (const float*)d_in[1];
  const int*   item_seq    = (const int*)d_in[2];
  const unsigned char* mask = (const unsigned char*)d_in[3];
  const float* U_w = (const float*)d_in[4];
  const float* W_w = (const float*)d_in[5];
  const float* V_w = (const float*)d_in[6];
  const float* E_w = (const float*)d_in[8];
  float* out = (float*)d_out;

  char* w = (char*)d_ws;
  u16* wsFeat = (u16*)w; w += (size_t)Bdim * Kdim2 * 2;         // 1 MB
  u16* wsLast = (u16*)w; w += (size_t)Hdim * Hdim * 2;          // 0.5 MB
  u16* wsW    = (u16*)w; w += (size_t)Hdim * Hdim * 2;
  u16* wsU    = (u16*)w; w += (size_t)Hdim * Hdim * 2;
  float* wsLm     = (float*)w; w += (size_t)Bdim * Hdim * 4;    // 1 MB
  float* wsScores = (float*)w; w += (size_t)Bdim * Sdim * 4;
  unsigned* wsSeen = (unsigned*)w; w += (size_t)Bdim * SEENW * 4;

  prep_kernel<<<256, 256, 0, stream>>>(last_memory, wsLast, W_w, wsW, U_w, wsU,
                                       wsScores, wsLm, wsSeen);
  scatter_kernel<<<100, 256, 0, stream>>>(item_seq, wsSeen);

  // lm = last_memory @ W_w^T   (512x512x512, split-K=4, atomic accumulate)
  gemm_bt<0><<<dim3(Hdim / BN, Bdim / BM, 4), 512, 0, stream>>>(
      wsLast, wsW, nullptr, Bdim, Hdim, Hdim, wsLm, nullptr, nullptr, nullptr);
  // scores += sum_k V[k]*tanh(am + lm)   (25600x512x512), 100 m x 4 n = 400 blocks
  gemm_bt<1><<<dim3((Bdim * Sdim / BM) * (Hdim / BN)), 512, 0, stream>>>(
      nullptr, wsU, all_memory, Bdim * Sdim, Hdim, Hdim, nullptr,
      wsLm, V_w, wsScores);
  softmax_ctx_kernel<<<Bdim, 256, 0, stream>>>(wsScores, mask, all_memory, last_memory, wsFeat);
  // out = sigmoid/mask( feat @ E_w^T )   (512x20000x1024), 157 n x 2 m = 314 blocks
  gemm_logits<<<dim3(((Ndim + LBN - 1) / LBN) * (Bdim / LBM)), 512, 0, stream>>>(
      wsFeat, E_w, out, wsSeen);
}

// Round 9
// 124.351 us; speedup vs baseline: 2.0462x; 1.3265x over previous
//
#include <hip/hip_runtime.h>
#include <hip/hip_bf16.h>

#define Bdim 512
#define Sdim 50
#define Hdim 512
#define Ndim 20000
#define Kdim2 1024   // 2*H
#define SEENW 640    // u32 words per row for the seen-bitmask (20000 bits -> 625, pad 640)

typedef __bf16 bf16x8 __attribute__((ext_vector_type(8)));
typedef float f32x4 __attribute__((ext_vector_type(4)));
typedef unsigned short u16;

#define AS1 __attribute__((address_space(1)))
#define AS3 __attribute__((address_space(3)))

__device__ __forceinline__ u16 f2bf(float f) {
  unsigned u = __builtin_bit_cast(unsigned, f);
  u = (u + 0x7fffu + ((u >> 16) & 1u)) >> 16;   // RNE
  return (u16)u;
}
// HW packed fp32->bf16 (RNE), lo -> [15:0], hi -> [31:16]
__device__ __forceinline__ unsigned cvt_pk_bf16(float lo, float hi) {
  unsigned r;
  asm("v_cvt_pk_bf16_f32 %0, %1, %2" : "=v"(r) : "v"(lo), "v"(hi));
  return r;
}
__device__ __forceinline__ bf16x8 pack8(float4 lo, float4 hi) {
  union { unsigned u[4]; bf16x8 v; } r;
  r.u[0] = cvt_pk_bf16(lo.x, lo.y);
  r.u[1] = cvt_pk_bf16(lo.z, lo.w);
  r.u[2] = cvt_pk_bf16(hi.x, hi.y);
  r.u[3] = cvt_pk_bf16(hi.z, hi.w);
  return r.v;
}

// ---------------- prep: cast last_memory/W_w/U_w + zero scores/lm/seen ----------
__global__ __launch_bounds__(256) void prep_kernel(const float* __restrict__ a, u16* __restrict__ da,
                                                   const float* __restrict__ b, u16* __restrict__ db,
                                                   const float* __restrict__ c, u16* __restrict__ dc,
                                                   float* __restrict__ scores, float* __restrict__ lm,
                                                   unsigned* __restrict__ seen) {
  int i = blockIdx.x * blockDim.x + threadIdx.x;   // 65536 threads, one float4 each
  float4 v; ushort4 o;
  v = reinterpret_cast<const float4*>(a)[i];
  o.x = f2bf(v.x); o.y = f2bf(v.y); o.z = f2bf(v.z); o.w = f2bf(v.w);
  reinterpret_cast<ushort4*>(da)[i] = o;
  v = reinterpret_cast<const float4*>(b)[i];
  o.x = f2bf(v.x); o.y = f2bf(v.y); o.z = f2bf(v.z); o.w = f2bf(v.w);
  reinterpret_cast<ushort4*>(db)[i] = o;
  v = reinterpret_cast<const float4*>(c)[i];
  o.x = f2bf(v.x); o.y = f2bf(v.y); o.z = f2bf(v.z); o.w = f2bf(v.w);
  reinterpret_cast<ushort4*>(dc)[i] = o;
  int stride = gridDim.x * blockDim.x;
  for (int j = i; j < Bdim * Sdim; j += stride) scores[j] = 0.f;
  for (int j = i; j < Bdim * Hdim; j += stride) lm[j] = 0.f;
  for (int j = i; j < Bdim * SEENW; j += stride) seen[j] = 0u;
}

// ---------------- seen-item scatter ----------------
__global__ __launch_bounds__(256) void scatter_kernel(const int* __restrict__ iseq,
                                                      unsigned* __restrict__ seen) {
  int i = blockIdx.x * blockDim.x + threadIdx.x;
  if (i < Bdim * Sdim) {
    int b = i / Sdim;
    int it = iseq[i];
    if (it > 0) atomicOr(&seen[b * SEENW + (it >> 5)], 1u << (it & 31));
  }
}

// ---------------- softmax over S + context readout -> feat (bf16) ----------------
__global__ __launch_bounds__(256) void softmax_ctx_kernel(
    const float* __restrict__ scores, const unsigned char* __restrict__ mask,
    const float* __restrict__ amF, const float* __restrict__ last_memory,
    u16* __restrict__ feat) {
  int b = blockIdx.x;
  __shared__ float alpha[Sdim];
  int tid = threadIdx.x;
  if (tid < 64) {
    float s = -1e30f;
    if (tid < Sdim) {
      s = scores[b * Sdim + tid];
      if (mask[b * Sdim + tid]) s = -1e9f;   // mask is all-false in this problem
    }
    float m = s;
#pragma unroll
    for (int off = 32; off; off >>= 1) m = fmaxf(m, __shfl_xor(m, off));
    float e = (tid < Sdim) ? __expf(s - m) : 0.f;
    float sum = e;
#pragma unroll
    for (int off = 32; off; off >>= 1) sum += __shfl_xor(sum, off);
    if (tid < Sdim) alpha[tid] = e / sum;
  }
  __syncthreads();
  for (int h = tid; h < Hdim; h += 256) {
    const float* amp = amF + ((long)b * Sdim) * Hdim + h;
    float c = 0.f;
#pragma unroll 5
    for (int s = 0; s < Sdim; ++s) c += alpha[s] * amp[(long)s * Hdim];
    feat[b * Kdim2 + h] = f2bf(c);
    feat[b * Kdim2 + Hdim + h] = f2bf(last_memory[b * Hdim + h]);
  }
}

// ---------------- gemm_bt: 2-phase schedule for lm GEMM (EPI0) + scores GEMM (EPI1)
#define BM 256
#define BN 128
#define BK 32

template <int EPI>
__global__ __launch_bounds__(512, 4) void gemm_bt(
    const u16* __restrict__ A, const u16* __restrict__ Bmat,
    const float* __restrict__ Af,
    int M, int N, int K,
    float* __restrict__ out,
    const float* __restrict__ lm, const float* __restrict__ Vw,
    float* __restrict__ scores) {
  __shared__ bf16x8 Asl[2][BM * BK / 8];   // 2 x 1024 chunks of 16B = 32 KB
  __shared__ bf16x8 Bsl[2][BN * BK / 8];   // 2 x  512 chunks of 16B = 16 KB
  const int tid = threadIdx.x;
  const int lane = tid & 63;
  const int wid = tid >> 6;                 // 0..7
  const int wr = wid >> 1, wc = wid & 1;    // 4x2 wave grid, 64x64 per wave
  const int la = lane & 15, lb = lane >> 4;

  int bx, by, kt0, kt1;
  if constexpr (EPI == 0) {
    bx = blockIdx.x; by = blockIdx.y;
    int ktotal = K / BK; int kper = ktotal / gridDim.z;
    kt0 = blockIdx.z * kper; kt1 = kt0 + kper;
  } else {
    int nwg = gridDim.x, bid = blockIdx.x;
    int q = nwg >> 3, r = nwg & 7;
    int x = bid & 7, i = bid >> 3;
    int wgid = (x < r ? x * (q + 1) : r * (q + 1) + (x - r) * q) + i;
    by = wgid >> 2; bx = wgid & 3;          // 4 n-tiles of one A m-panel per XCD
    kt0 = 0; kt1 = K / BK;
  }
  const int m0 = by * BM;
  const int n0 = bx * BN;

  f32x4 acc[4][4];
  const f32x4 zero = {0.f, 0.f, 0.f, 0.f};
#pragma unroll
  for (int i = 0; i < 4; ++i)
#pragma unroll
    for (int j = 0; j < 4; ++j) acc[i][j] = zero;

  const int rw = tid >> 2;
  const int eA = (tid & 3) * 8;
  const int ch = tid & 3;
  int brB = n0 + rw; if (brB > N - 1) brB = N - 1;

  const u16 *gA0 = nullptr, *gA1 = nullptr, *gB = nullptr;
  const float *gAf0 = nullptr, *gAf1 = nullptr;
  if constexpr (EPI == 1) {
    gAf0 = Af + (long)(m0 + rw) * K + eA;
    gAf1 = Af + (long)(m0 + 128 + rw) * K + eA;
  } else {
    gA0 = A + (long)(m0 + rw) * K + eA;
    gA1 = A + (long)(m0 + 128 + rw) * K + eA;
  }
  gB = Bmat + (long)brB * K + eA;

  float4 ra0, ra1, ra2, ra3;   // EPI1: A fp32 staging regs

  auto STAGE_G = [&](int buf, int kt) {
    const int k0 = kt * BK;
    if constexpr (EPI != 1) {
      __builtin_amdgcn_global_load_lds((const AS1 void*)(gA0 + k0),
                                       (AS3 void*)(void*)&Asl[buf][wid * 64], 16, 0, 0);
      __builtin_amdgcn_global_load_lds((const AS1 void*)(gA1 + k0),
                                       (AS3 void*)(void*)&Asl[buf][512 + wid * 64], 16, 0, 0);
    }
    __builtin_amdgcn_global_load_lds((const AS1 void*)(gB + k0),
                                     (AS3 void*)(void*)&Bsl[buf][wid * 64], 16, 0, 0);
  };
  auto LOADR = [&](int kt) {
    const int k0 = kt * BK;
    if constexpr (EPI == 1) {
      ra0 = *reinterpret_cast<const float4*>(gAf0 + k0);
      ra1 = *reinterpret_cast<const float4*>(gAf0 + k0 + 4);
      ra2 = *reinterpret_cast<const float4*>(gAf1 + k0);
      ra3 = *reinterpret_cast<const float4*>(gAf1 + k0 + 4);
    }
  };
  auto WRITER = [&](int buf) {
    if constexpr (EPI == 1) {
      Asl[buf][rw * 4 + ch] = pack8(ra0, ra1);
      Asl[buf][(128 + rw) * 4 + ch] = pack8(ra2, ra3);
    }
  };

  STAGE_G(0, kt0);
  LOADR(kt0);
  WRITER(0);
  __syncthreads();
  int cur = 0;
  for (int kt = kt0; kt < kt1; ++kt) {
    const bool pf = (kt + 1 < kt1);
    if (pf) { STAGE_G(cur ^ 1, kt + 1); LOADR(kt + 1); }

    bf16x8 af[4], bfr[4];
#pragma unroll
    for (int mi = 0; mi < 4; ++mi)
      af[mi] = Asl[cur][(wr * 64 + mi * 16 + la) * 4 + lb];
#pragma unroll
    for (int ni = 0; ni < 4; ++ni)
      bfr[ni] = Bsl[cur][(wc * 64 + ni * 16 + la) * 4 + lb];
#pragma unroll
    for (int mi = 0; mi < 4; ++mi)
#pragma unroll
      for (int ni = 0; ni < 4; ++ni)
        acc[mi][ni] = __builtin_amdgcn_mfma_f32_16x16x32_bf16(af[mi], bfr[ni], acc[mi][ni], 0, 0, 0);

    if (pf) WRITER(cur ^ 1);
    __syncthreads();
    cur ^= 1;
  }

  // C/D layout (verified): col = lane&15, row = (lane>>4)*4 + reg
  if constexpr (EPI == 0) {
#pragma unroll
    for (int mi = 0; mi < 4; ++mi)
#pragma unroll
      for (int i = 0; i < 4; ++i) {
        int r = m0 + wr * 64 + mi * 16 + lb * 4 + i;
#pragma unroll
        for (int ni = 0; ni < 4; ++ni) {
          int c = n0 + wc * 64 + ni * 16 + la;
          atomicAdd(&out[(long)r * N + c], acc[mi][ni][i]);
        }
      }
  }
  if constexpr (EPI == 1) {
#pragma unroll
    for (int mi = 0; mi < 4; ++mi)
#pragma unroll
      for (int i = 0; i < 4; ++i) {
        int r = m0 + wr * 64 + mi * 16 + lb * 4 + i;
        int bidx = r / Sdim;
        float p = 0.f;
#pragma unroll
        for (int ni = 0; ni < 4; ++ni) {
          int c = n0 + wc * 64 + ni * 16 + la;
          float x = acc[mi][ni][i] + lm[bidx * Hdim + c];
          x = fminf(fmaxf(x, -9.f), 9.f);
          float e = __expf(2.f * x);
          p += Vw[c] * ((e - 1.f) / (e + 1.f));
        }
        p += __shfl_xor(p, 1);
        p += __shfl_xor(p, 2);
        p += __shfl_xor(p, 4);
        p += __shfl_xor(p, 8);
        if (la == 0) atomicAdd(&scores[r], p);
      }
  }
}

// ---------------- gemm_logits v3: many-block 2-phase, fused fp32->bf16 B ------
// Rebuilt on the EPI1 recipe (the one fused-cast GEMM that works):
//  * 128x128 tile, 256 threads (2x2 waves), BK=32 -> grid 628 blocks
//    (~2.5 blocks/CU: inter-block latency overlap = m97's implicit pipeline;
//    r5-r8's 314x512t had ~1.2/CU and every schedule trick failed)
//  * XCD swizzle groups the FOUR m-tiles of one E-panel on one XCD
//    (75% of the fp32 E stream becomes L2 hits; was 2-way/50% before)
//  * plain 2-phase __syncthreads loop, NO fences, NO raw barriers (m141:
//    fences defeat the compiler; syncthreads' vmcnt(0) drain makes >1-deep
//    reg prefetch pointless anyway)
//  * B = E_w fp32 reg-staged: 4x float4 at iter top (single named bank),
//    cvt_pk + swizzled ds_write after MFMA; A = feat bf16 via global_load_lds
//    with pre-swizzled source (both-sides XOR chunk swizzle, read kch=lb^(la&3))
#define LBM 128
#define LBN 128
#define LBK 32

__global__ __launch_bounds__(256) void gemm_logits(
    const u16* __restrict__ A, const float* __restrict__ Bf,
    float* __restrict__ out, const unsigned* __restrict__ seen) {
  __shared__ bf16x8 Asl[2][LBM * LBK / 8];   // 2 x 8 KB
  __shared__ bf16x8 Bsl[2][LBN * LBK / 8];   // 2 x 8 KB
  const int tid = threadIdx.x;
  const int lane = tid & 63;
  const int wid = tid >> 6;                  // 0..3
  const int wr = wid >> 1, wc = wid & 1;     // 2x2 waves, 64x64 per wave
  const int la = lane & 15, lb = lane >> 4;
  const int kch = lb ^ (la & 3);             // swizzled k-chunk for LDS reads
  const int NT = Kdim2 / LBK;                // 32

  // bijective XCD swizzle; groups the 4 m-tiles of one E_w n-panel per XCD
  int nwg = gridDim.x, bid = blockIdx.x;
  int q = nwg >> 3, r = nwg & 7;
  int x = bid & 7, i0 = bid >> 3;
  int wgid = (x < r ? x * (q + 1) : r * (q + 1) + (x - r) * q) + i0;
  const int bx = wgid >> 2, by = wgid & 3;   // 157 n-tiles x 4 m-tiles
  const int m0 = by * LBM, n0 = bx * LBN;

  f32x4 acc[4][4];
  const f32x4 zero = {0.f, 0.f, 0.f, 0.f};
#pragma unroll
  for (int i = 0; i < 4; ++i)
#pragma unroll
    for (int j = 0; j < 4; ++j) acc[i][j] = zero;

  // A staging: 512 chunks of 16B per tile; thread t covers chunks t and t+256
  // (rows t>>2 and 64+(t>>2), chunk-in-row t&3). Source k-chunk pre-swizzled
  // so linear gload_lds dest yields physical layout chunk^(row&3).
  const int rA = tid >> 2;
  const int swzA = (tid & 3) ^ (rA & 3);
  const u16* gA0 = A + (long)(m0 + rA) * Kdim2 + swzA * 8;
  const u16* gA1 = A + (long)(m0 + 64 + rA) * Kdim2 + swzA * 8;

  // B staging: 128 rows x 32 fp32 = 16 KB; 2 threads/row, 16 floats each.
  const int rB = tid >> 1;
  const int hB = tid & 1;                    // k-half: floats [hB*16, hB*16+16)
  int brB = n0 + rB; if (brB > Ndim - 1) brB = Ndim - 1;
  const float* gBf = Bf + (long)brB * Kdim2 + hB * 16;
  const int bw0 = rB * 4 + ((2 * hB) ^ (rB & 3));       // swizzled write chunks
  const int bw1 = rB * 4 + ((2 * hB + 1) ^ (rB & 3));

  float4 q0, q1, q2, q3;   // single B reg bank (loaded top, consumed bottom)

  auto STAGE_A = [&](int buf, int kt) {
    const int k0 = kt * LBK;
    __builtin_amdgcn_global_load_lds((const AS1 void*)(gA0 + k0),
                                     (AS3 void*)(void*)&Asl[buf][wid * 64], 16, 0, 0);
    __builtin_amdgcn_global_load_lds((const AS1 void*)(gA1 + k0),
                                     (AS3 void*)(void*)&Asl[buf][256 + wid * 64], 16, 0, 0);
  };
  auto BLOAD = [&](int kt) {
    const int k0 = kt * LBK;
    q0 = *reinterpret_cast<const float4*>(gBf + k0);
    q1 = *reinterpret_cast<const float4*>(gBf + k0 + 4);
    q2 = *reinterpret_cast<const float4*>(gBf + k0 + 8);
    q3 = *reinterpret_cast<const float4*>(gBf + k0 + 12);
  };
  auto BWRITE = [&](int buf) {
    Bsl[buf][bw0] = pack8(q0, q1);
    Bsl[buf][bw1] = pack8(q2, q3);
  };

  STAGE_A(0, 0);
  BLOAD(0);
  BWRITE(0);
  __syncthreads();
  int cur = 0;
  for (int kt = 0; kt < NT; ++kt) {
    const bool pf = (kt + 1 < NT);
    if (pf) { STAGE_A(cur ^ 1, kt + 1); BLOAD(kt + 1); }

    bf16x8 af[4], bfr[4];
#pragma unroll
    for (int mi = 0; mi < 4; ++mi)
      af[mi] = Asl[cur][(wr * 64 + mi * 16 + la) * 4 + kch];
#pragma unroll
    for (int ni = 0; ni < 4; ++ni)
      bfr[ni] = Bsl[cur][(wc * 64 + ni * 16 + la) * 4 + kch];
#pragma unroll
    for (int mi = 0; mi < 4; ++mi)
#pragma unroll
      for (int ni = 0; ni < 4; ++ni)
        acc[mi][ni] = __builtin_amdgcn_mfma_f32_16x16x32_bf16(af[mi], bfr[ni], acc[mi][ni], 0, 0, 0);

    if (pf) BWRITE(cur ^ 1);
    __syncthreads();
    cur ^= 1;
  }

  // epilogue: sigmoid + seen-mask
#pragma unroll
  for (int mi = 0; mi < 4; ++mi)
#pragma unroll
    for (int i = 0; i < 4; ++i) {
      int r = m0 + wr * 64 + mi * 16 + lb * 4 + i;
      long rb = (long)r * Ndim;
#pragma unroll
      for (int ni = 0; ni < 4; ++ni) {
        int c = n0 + wc * 64 + ni * 16 + la;
        if (c < Ndim) {
          unsigned wbits = seen[r * SEENW + (c >> 5)];
          float val = 0.f;
          if (!((wbits >> (c & 31)) & 1u))
            val = 1.f / (1.f + __expf(-acc[mi][ni][i]));
          out[rb + c] = val;
        }
      }
    }
}

// ---------------- launcher ----------------
extern "C" void kernel_launch(void* const* d_in, const int* in_sizes, int n_in,
                              void* d_out, int out_size, void* d_ws, size_t ws_size,
                              hipStream_t stream) {
  (void)in_sizes; (void)n_in; (void)out_size; (void)ws_size;
  const float* all_memory  = (const float*)d_in[0];
  const float* last_memory = (const float*)d_in[1];
  const int*   item_seq    = (const int*)d_in[2];
  const unsigned char* mask = (const unsigned char*)d_in[3];
  const float* U_w = (const float*)d_in[4];
  const float* W_w = (const float*)d_in[5];
  const float* V_w = (const float*)d_in[6];
  const float* E_w = (const float*)d_in[8];
  float* out = (float*)d_out;

  char* w = (char*)d_ws;
  u16* wsFeat = (u16*)w; w += (size_t)Bdim * Kdim2 * 2;         // 1 MB
  u16* wsLast = (u16*)w; w += (size_t)Hdim * Hdim * 2;          // 0.5 MB
  u16* wsW    = (u16*)w; w += (size_t)Hdim * Hdim * 2;
  u16* wsU    = (u16*)w; w += (size_t)Hdim * Hdim * 2;
  float* wsLm     = (float*)w; w += (size_t)Bdim * Hdim * 4;    // 1 MB
  float* wsScores = (float*)w; w += (size_t)Bdim * Sdim * 4;
  unsigned* wsSeen = (unsigned*)w; w += (size_t)Bdim * SEENW * 4;

  prep_kernel<<<256, 256, 0, stream>>>(last_memory, wsLast, W_w, wsW, U_w, wsU,
                                       wsScores, wsLm, wsSeen);
  scatter_kernel<<<100, 256, 0, stream>>>(item_seq, wsSeen);

  // lm = last_memory @ W_w^T   (512x512x512, split-K=4, atomic accumulate)
  gemm_bt<0><<<dim3(Hdim / BN, Bdim / BM, 4), 512, 0, stream>>>(
      wsLast, wsW, nullptr, Bdim, Hdim, Hdim, wsLm, nullptr, nullptr, nullptr);
  // scores += sum_k V[k]*tanh(am + lm)   (25600x512x512), 100 m x 4 n = 400 blocks
  gemm_bt<1><<<dim3((Bdim * Sdim / BM) * (Hdim / BN)), 512, 0, stream>>>(
      nullptr, wsU, all_memory, Bdim * Sdim, Hdim, Hdim, nullptr,
      wsLm, V_w, wsScores);
  softmax_ctx_kernel<<<Bdim, 256, 0, stream>>>(wsScores, mask, all_memory, last_memory, wsFeat);
  // out = sigmoid/mask( feat @ E_w^T )  (512x20000x1024), 157 n x 4 m = 628 blocks
  gemm_logits<<<dim3(((Ndim + LBN - 1) / LBN) * (Bdim / LBM)), 256, 0, stream>>>(
      wsFeat, E_w, out, wsSeen);
}